// Round 13
// baseline (57.202 us; speedup 1.0000x reference)
//
#include <hip/hip_runtime.h>

#define Bn 4
#define Tn 2048
#define Dn 1024
#define HSn 64

typedef __attribute__((ext_vector_type(8))) short bf16x8;
typedef __attribute__((ext_vector_type(4))) float f32x4;
typedef __attribute__((ext_vector_type(4))) short s16x4;
typedef unsigned short u16;
typedef unsigned int u32;

__device__ __forceinline__ u16 f2bf_rne(float x) {
    u32 u = __float_as_uint(x);
    return (u16)((u + 0x7FFFu + ((u >> 16) & 1u)) >> 16);
}
__device__ __forceinline__ u16 f2bf_trunc(float x) {
    return (u16)(__float_as_uint(x) >> 16);
}
__device__ __forceinline__ float bf2f(u16 h) {
    return __uint_as_float(((u32)h) << 16);
}

// ---------------- Prep: W^T hi/lo bf16, fragment-tiled (round-9 verified) ----------------
// Fragment load for k-step ks, col-tile nt: wtp2 + (ks*12+nt)*1024 + hl*512 + lane*8
__global__ __launch_bounds__(256) void wprep_kernel(
    const float* __restrict__ Wk, const float* __restrict__ Wq,
    const float* __restrict__ Wv, u16* __restrict__ wtp2)
{
    __shared__ float ws_[64][65];
    const int kb = blockIdx.x;        // k-block of 64
    const int w  = blockIdx.y;        // 0=Wk,1=Wq,2=Wv
    const float* __restrict__ W = (w == 0) ? Wk : (w == 1) ? Wq : Wv;
    const float scale = (w == 1) ? 8.0f : 1.0f;   // fold *sqrt(HS) into Wq
    const int t = threadIdx.x;

    {
        const int kl = t >> 2, hq = t & 3;
        #pragma unroll
        for (int i = 0; i < 4; ++i) {
            float4 f = *(const float4*)(W + (size_t)(kb * 64 + kl) * 64 + hq * 16 + i * 4);
            ws_[kl][hq * 16 + i * 4 + 0] = f.x; ws_[kl][hq * 16 + i * 4 + 1] = f.y;
            ws_[kl][hq * 16 + i * 4 + 2] = f.z; ws_[kl][hq * 16 + i * 4 + 3] = f.w;
        }
    }
    __syncthreads();

    const int h = t & 63, quarter = t >> 6;
    const int nt = w * 4 + (h >> 4);
    const int ksub = quarter >> 1;
    u16 hib[16], lob[16];
    #pragma unroll
    for (int j = 0; j < 16; ++j) {
        float v = ws_[quarter * 16 + j][h] * scale;
        u16 hi = f2bf_trunc(v);
        hib[j] = hi;
        lob[j] = f2bf_trunc(v - bf2f(hi));
    }
    const int lane0 = ((quarter * 2 + 0) & 3) * 16 + (h & 15);
    const int lane1 = ((quarter * 2 + 1) & 3) * 16 + (h & 15);
    u16* base = wtp2 + (size_t)kb * 24576 + (size_t)(ksub * 12 + nt) * 1024;
    *(uint4*)(base + lane0 * 8)       = *(const uint4*)&hib[0];
    *(uint4*)(base + lane1 * 8)       = *(const uint4*)&hib[8];
    *(uint4*)(base + 512 + lane0 * 8) = *(const uint4*)&lob[0];
    *(uint4*)(base + 512 + lane1 * 8) = *(const uint4*)&lob[8];
}

// ---------------- Projection GEMM v3: barrier-free, all-register (attn-style) ----------------
// 512 blocks x 256 threads; block = 16 rows x 192 cols; wave = 16r x 3 col-tiles.
// A: 2 dwordx4/lane from x; B: 6 dwordx4/lane from fragment-tiled wtp2 (1KB coalesced).
// Double-buffered reg sets, no LDS, no barriers; compiler-managed waitcnt.
#define NKS 32

struct Pset {
    f32x4 xa, xb;
    bf16x8 bh[3], bl[3];
};

__global__ __launch_bounds__(256) void proj_gemm(
    const float* __restrict__ x, const u16* __restrict__ wtp2,
    u16* __restrict__ qh8, u16* __restrict__ ql8,
    u16* __restrict__ kth, u16* __restrict__ ktl,
    u16* __restrict__ vtt)
{
    const int tid  = threadIdx.x;
    const int wave = tid >> 6, lane = tid & 63;
    const int lo4  = lane & 15, g = lane >> 4;
    const int row0 = blockIdx.x * 16;
    const int nt0  = wave * 3;                 // first col-tile of this wave

    f32x4 acc[3];
    #pragma unroll
    for (int c = 0; c < 3; ++c) acc[c] = (f32x4){0.f, 0.f, 0.f, 0.f};

    const float* ap0 = x + (size_t)(row0 + lo4) * Dn + g * 8;
    const u16*   bp0 = wtp2 + (size_t)nt0 * 1024 + lane * 8;

    #define LOADP(S, KS)                                                      \
        {                                                                     \
            const float* ap = ap0 + (KS) * 32;                                \
            S.xa = *(const f32x4*)(ap);                                       \
            S.xb = *(const f32x4*)(ap + 4);                                   \
            const u16* bp = bp0 + (size_t)(KS) * 12288;                       \
            _Pragma("unroll")                                                 \
            for (int ct = 0; ct < 3; ++ct) {                                  \
                S.bh[ct] = *(const bf16x8*)(bp + ct * 1024);                  \
                S.bl[ct] = *(const bf16x8*)(bp + ct * 1024 + 512);            \
            }                                                                 \
        }

    #define COMPUTEP(S)                                                      \
        {                                                                    \
            bf16x8 ah, al;                                                   \
            _Pragma("unroll")                                                \
            for (int jj = 0; jj < 4; ++jj) {                                 \
                u16 h0 = f2bf_trunc(S.xa[jj]);                               \
                ah[jj] = (short)h0;                                          \
                al[jj] = (short)f2bf_trunc(S.xa[jj] - bf2f(h0));             \
                u16 h1 = f2bf_trunc(S.xb[jj]);                               \
                ah[4 + jj] = (short)h1;                                      \
                al[4 + jj] = (short)f2bf_trunc(S.xb[jj] - bf2f(h1));         \
            }                                                                \
            __builtin_amdgcn_s_setprio(1);                                   \
            _Pragma("unroll")                                                \
            for (int ct = 0; ct < 3; ++ct) {                                 \
                acc[ct] = __builtin_amdgcn_mfma_f32_16x16x32_bf16(ah, S.bh[ct], acc[ct], 0, 0, 0); \
                acc[ct] = __builtin_amdgcn_mfma_f32_16x16x32_bf16(al, S.bh[ct], acc[ct], 0, 0, 0); \
                acc[ct] = __builtin_amdgcn_mfma_f32_16x16x32_bf16(ah, S.bl[ct], acc[ct], 0, 0, 0); \
            }                                                                \
            __builtin_amdgcn_s_setprio(0);                                   \
        }

    Pset A, B;
    LOADP(A, 0)
    for (int ks = 0; ks < NKS; ks += 2) {
        LOADP(B, ks + 1)
        COMPUTEP(A)
        if (ks + 2 < NKS) LOADP(A, ks + 2)
        COMPUTEP(B)
    }

    // epilogue: C layout col=lane&15, row=g*4+reg; fragment-tiled K/V outputs
    const int grow = row0 + g * 4;
    const int bb_ = grow >> 11, tl = grow & 2047;
    #pragma unroll
    for (int ct = 0; ct < 3; ++ct) {
        const int n = (nt0 + ct) * 16 + lo4;
        if (n < 64) {
            const int kch = n >> 5, gi = (n >> 3) & 3, e = n & 7;
            const size_t base = (size_t)bb_ * 131072
                + (size_t)(((((tl >> 4) * 2 + kch) * 4 + gi) * 16 + (tl & 15)) * 8 + e);
            #pragma unroll
            for (int reg = 0; reg < 4; ++reg) {
                float v = acc[ct][reg];
                u16 hi = f2bf_trunc(v);
                kth[base + reg * 8] = hi;
                ktl[base + reg * 8] = f2bf_trunc(v - bf2f(hi));
            }
        } else if (n < 128) {
            #pragma unroll
            for (int reg = 0; reg < 4; ++reg) {
                float v = acc[ct][reg];   // already *8 (folded into Wq)
                u16 hi = f2bf_trunc(v);
                qh8[(size_t)(grow + reg) * HSn + (n - 64)] = hi;
                ql8[(size_t)(grow + reg) * HSn + (n - 64)] = f2bf_trunc(v - bf2f(hi));
            }
        } else {
            const int h = n - 128;
            s16x4 pack;
            #pragma unroll
            for (int reg = 0; reg < 4; ++reg)
                pack[reg] = (short)f2bf_rne(acc[ct][reg]);
            const size_t vidx = (size_t)bb_ * 131072
                + (size_t)((tl >> 5) * 2048 + (h >> 4) * 512 + (h & 15) * 32
                           + ((tl >> 3) & 3) * 8 + (tl & 7));
            *(s16x4*)(vtt + vidx) = pack;
        }
    }
}

// ---------------- MFMA flash attention v4: l via MFMA(P, ones) ----------------
struct KVset {
    bf16x8 kh0[2], kh1[2], kl0[2], kl1[2], vf[4];
};

__global__ __launch_bounds__(256, 2) void attn_kernel(
    const u16* __restrict__ qh8, const u16* __restrict__ ql8,
    const u16* __restrict__ kth, const u16* __restrict__ ktl,
    const u16* __restrict__ vtt, float* __restrict__ out)
{
    __shared__ __align__(16) unsigned char pbuf[4096];
    __shared__ __align__(16) float om_s[4][16][64];
    __shared__ float ml_s[4][16][2];

    const int tid  = threadIdx.x;
    const int wave = tid >> 6, lane = tid & 63;
    const int lo4  = lane & 15, g = lane >> 4;

    const int sblk = blockIdx.x >> 8, c = blockIdx.x & 255;
    const int tb = sblk ? 127 - (c >> 1) : (c >> 1);
    const int b  = 2 * sblk + (c & 1);
    const int t0 = tb * 16;

    const u16* qhp = qh8 + ((size_t)b * Tn + t0) * HSn;
    const u16* qlp = ql8 + ((size_t)b * Tn + t0) * HSn;
    const u16* kthb = kth + (size_t)b * 131072;
    const u16* ktlb = ktl + (size_t)b * 131072;
    const u16* vttb = vtt + (size_t)b * 131072;
    const int klane = lane * 8;
    const int vlane = lo4 * 32 + g * 8;

    bf16x8 qfh[2], qfl[2];
    #pragma unroll
    for (int ch = 0; ch < 2; ++ch) {
        qfh[ch] = *(const bf16x8*)(qhp + lo4 * HSn + ch * 32 + g * 8);
        qfl[ch] = *(const bf16x8*)(qlp + lo4 * HSn + ch * 32 + g * 8);
    }

    bf16x8 vones;
    #pragma unroll
    for (int i = 0; i < 8; ++i) vones[i] = (short)0x3F80;   // bf16 1.0

    f32x4 O[4];
    #pragma unroll
    for (int n = 0; n < 4; ++n) O[n] = (f32x4){0.f, 0.f, 0.f, 0.f};
    float mrow[4], lrow[4];
    #pragma unroll
    for (int r = 0; r < 4; ++r) { mrow[r] = -1e30f; lrow[r] = 0.f; }

    const int nt = (t0 + 15) / 32 + 1;
    unsigned char* myPB = pbuf + wave * 1024;

    #define LOADSET(S, J)                                                     \
        {                                                                     \
            const u16* kb_ = kthb + (size_t)(2 * (J)) * 1024 + klane;         \
            const u16* lb_ = ktlb + (size_t)(2 * (J)) * 1024 + klane;         \
            S.kh0[0] = *(const bf16x8*)(kb_);                                 \
            S.kh1[0] = *(const bf16x8*)(kb_ + 512);                           \
            S.kh0[1] = *(const bf16x8*)(kb_ + 1024);                          \
            S.kh1[1] = *(const bf16x8*)(kb_ + 1536);                          \
            S.kl0[0] = *(const bf16x8*)(lb_);                                 \
            S.kl1[0] = *(const bf16x8*)(lb_ + 512);                           \
            S.kl0[1] = *(const bf16x8*)(lb_ + 1024);                          \
            S.kl1[1] = *(const bf16x8*)(lb_ + 1536);                          \
            const u16* vb_ = vttb + (size_t)(J) * 2048 + vlane;               \
            S.vf[0] = *(const bf16x8*)(vb_);                                  \
            S.vf[1] = *(const bf16x8*)(vb_ + 512);                            \
            S.vf[2] = *(const bf16x8*)(vb_ + 1024);                           \
            S.vf[3] = *(const bf16x8*)(vb_ + 1536);                           \
        }

    #define COMPUTE_ATT(S, J)                                                 \
        {                                                                     \
            const int s0 = (J) * 32;                                          \
            f32x4 accS[2];                                                    \
            __builtin_amdgcn_s_setprio(1);                                    \
            _Pragma("unroll")                                                 \
            for (int sb = 0; sb < 2; ++sb) {                                  \
                f32x4 a = (f32x4){0.f, 0.f, 0.f, 0.f};                        \
                a = __builtin_amdgcn_mfma_f32_16x16x32_bf16(qfh[0], S.kh0[sb], a, 0, 0, 0); \
                a = __builtin_amdgcn_mfma_f32_16x16x32_bf16(qfh[1], S.kh1[sb], a, 0, 0, 0); \
                a = __builtin_amdgcn_mfma_f32_16x16x32_bf16(qfl[0], S.kh0[sb], a, 0, 0, 0); \
                a = __builtin_amdgcn_mfma_f32_16x16x32_bf16(qfl[1], S.kh1[sb], a, 0, 0, 0); \
                a = __builtin_amdgcn_mfma_f32_16x16x32_bf16(qfh[0], S.kl0[sb], a, 0, 0, 0); \
                a = __builtin_amdgcn_mfma_f32_16x16x32_bf16(qfh[1], S.kl1[sb], a, 0, 0, 0); \
                accS[sb] = a;                                                 \
            }                                                                 \
            __builtin_amdgcn_s_setprio(0);                                    \
            _Pragma("unroll")                                                 \
            for (int reg = 0; reg < 4; ++reg) {                               \
                const int tg  = t0 + g * 4 + reg;                             \
                const int sg0 = s0 + lo4;                                     \
                const int sg1 = s0 + 16 + lo4;                                \
                float v0 = (sg0 <= tg) ? accS[0][reg] : -1e30f;               \
                float v1 = (sg1 <= tg) ? accS[1][reg] : -1e30f;               \
                float mt = fmaxf(v0, v1);                                     \
                mt = fmaxf(mt, __shfl_xor(mt, 1));                            \
                mt = fmaxf(mt, __shfl_xor(mt, 2));                            \
                mt = fmaxf(mt, __shfl_xor(mt, 4));                            \
                mt = fmaxf(mt, __shfl_xor(mt, 8));                            \
                float mn = fmaxf(mrow[reg], mt);                              \
                float p0 = (sg0 <= tg) ? __expf(v0 - mn) : 0.f;               \
                float p1 = (sg1 <= tg) ? __expf(v1 - mn) : 0.f;               \
                float alpha = __expf(mrow[reg] - mn);                         \
                lrow[reg] *= alpha;           /* row-sum added via MFMA below */ \
                mrow[reg] = mn;                                               \
                _Pragma("unroll")                                             \
                for (int n = 0; n < 4; ++n) O[n][reg] *= alpha;               \
                const int irow = g * 4 + reg;                                 \
                *(u16*)(myPB + ((irow * 64 + lo4 * 2) ^ (reg << 4)))      = f2bf_rne(p0); \
                *(u16*)(myPB + ((irow * 64 + 32 + lo4 * 2) ^ (reg << 4))) = f2bf_rne(p1); \
            }                                                                 \
            bf16x8 pf = *(const bf16x8*)(myPB + ((lo4 * 64 + 16 * g) ^ ((lo4 & 3) << 4))); \
            __builtin_amdgcn_s_setprio(1);                                    \
            f32x4 lacc = (f32x4){0.f, 0.f, 0.f, 0.f};                         \
            lacc = __builtin_amdgcn_mfma_f32_16x16x32_bf16(pf, vones, lacc, 0, 0, 0); \
            _Pragma("unroll")                                                 \
            for (int n = 0; n < 4; ++n)                                       \
                O[n] = __builtin_amdgcn_mfma_f32_16x16x32_bf16(pf, S.vf[n], O[n], 0, 0, 0); \
            __builtin_amdgcn_s_setprio(0);                                    \
            _Pragma("unroll")                                                 \
            for (int reg = 0; reg < 4; ++reg) lrow[reg] += lacc[reg];         \
        }

    KVset A, B;
    int j = wave;
    if (j < nt) LOADSET(A, j)
    while (j < nt) {
        if (j + 4 < nt) LOADSET(B, j + 4)
        COMPUTE_ATT(A, j)
        if (j + 4 < nt) {
            if (j + 8 < nt) LOADSET(A, j + 8)
            COMPUTE_ATT(B, j + 4)
        }
        j += 8;
    }

    // per-wave partials -> LDS
    #pragma unroll
    for (int n = 0; n < 4; ++n)
        #pragma unroll
        for (int reg = 0; reg < 4; ++reg)
            om_s[wave][g * 4 + reg][n * 16 + lo4] = O[n][reg];
    if (lo4 == 0) {
        #pragma unroll
        for (int reg = 0; reg < 4; ++reg) {
            ml_s[wave][g * 4 + reg][0] = mrow[reg];
            ml_s[wave][g * 4 + reg][1] = lrow[reg];
        }
    }
    __syncthreads();

    const int r  = tid >> 4;
    const int h4 = (tid & 15) * 4;
    float mw[4], lw[4], mstar = -1e30f;
    #pragma unroll
    for (int w = 0; w < 4; ++w) {
        mw[w] = ml_s[w][r][0];
        lw[w] = ml_s[w][r][1];
        mstar = fmaxf(mstar, mw[w]);
    }
    float lstar = 0.f, ew[4];
    #pragma unroll
    for (int w = 0; w < 4; ++w) { ew[w] = __expf(mw[w] - mstar); lstar += lw[w] * ew[w]; }
    float4 a4 = {0.f, 0.f, 0.f, 0.f};
    #pragma unroll
    for (int w = 0; w < 4; ++w) {
        float4 t4 = *(const float4*)&om_s[w][r][h4];
        a4.x += t4.x * ew[w]; a4.y += t4.y * ew[w];
        a4.z += t4.z * ew[w]; a4.w += t4.w * ew[w];
    }
    const float inv = 1.f / lstar;
    a4.x *= inv; a4.y *= inv; a4.z *= inv; a4.w *= inv;
    *(float4*)(out + ((size_t)b * Tn + t0 + r) * HSn + h4) = a4;
}

extern "C" void kernel_launch(void* const* d_in, const int* in_sizes, int n_in,
                              void* d_out, int out_size, void* d_ws, size_t ws_size,
                              hipStream_t stream) {
    const float* x  = (const float*)d_in[0];
    const float* Wk = (const float*)d_in[1];
    const float* Wq = (const float*)d_in[2];
    const float* Wv = (const float*)d_in[3];
    float* out = (float*)d_out;

    const size_t per = (size_t)Bn * Tn * HSn;   // 524288
    u16* qh8 = (u16*)d_ws;
    u16* ql8 = qh8 + per;
    u16* kth = ql8 + per;
    u16* ktl = kth + per;
    u16* vtt = ktl + per;
    u16* wtp2 = vtt + per;                      // 16*24576 u16 = 768 KB

    hipLaunchKernelGGL(wprep_kernel, dim3(16, 3), dim3(256), 0, stream,
                       Wk, Wq, Wv, wtp2);
    hipLaunchKernelGGL(proj_gemm, dim3(512), dim3(256), 0, stream,
                       x, wtp2, qh8, ql8, kth, ktl, vtt);
    hipLaunchKernelGGL(attn_kernel, dim3(512), dim3(256), 0, stream,
                       qh8, ql8, kth, ktl, vtt, out);
}

// Round 14
// 45.718 us; speedup vs baseline: 1.2512x; 1.2512x over previous
//
#include <hip/hip_runtime.h>

#define Bn 4
#define Tn 2048
#define Dn 1024
#define HSn 64

typedef __attribute__((ext_vector_type(8))) short bf16x8;
typedef __attribute__((ext_vector_type(4))) float f32x4;
typedef __attribute__((ext_vector_type(4))) short s16x4;
typedef unsigned short u16;
typedef unsigned int u32;

__device__ __forceinline__ u16 f2bf_rne(float x) {
    u32 u = __float_as_uint(x);
    return (u16)((u + 0x7FFFu + ((u >> 16) & 1u)) >> 16);
}
__device__ __forceinline__ u16 f2bf_trunc(float x) {
    return (u16)(__float_as_uint(x) >> 16);
}
__device__ __forceinline__ float bf2f(u16 h) {
    return __uint_as_float(((u32)h) << 16);
}

#define GLL16(g, l)                                                        \
    __builtin_amdgcn_global_load_lds(                                      \
        (const __attribute__((address_space(1))) void*)(g),                \
        (__attribute__((address_space(3))) void*)(l), 16, 0, 0)

// ---------------- Prep: W^T hi/lo bf16, packed per k-step ----------------
__global__ __launch_bounds__(256) void wprep_kernel(
    const float* __restrict__ Wk, const float* __restrict__ Wq,
    const float* __restrict__ Wv, u16* __restrict__ wtp)
{
    __shared__ float ws_[64][65];
    const int kb = blockIdx.x;
    const int w  = blockIdx.y;
    const float* __restrict__ W = (w == 0) ? Wk : (w == 1) ? Wq : Wv;
    const float scale = (w == 1) ? 8.0f : 1.0f;
    const int t = threadIdx.x;

    {
        const int kl = t >> 2, hq = t & 3;
        #pragma unroll
        for (int i = 0; i < 4; ++i) {
            float4 f = *(const float4*)(W + (size_t)(kb * 64 + kl) * 64 + hq * 16 + i * 4);
            ws_[kl][hq * 16 + i * 4 + 0] = f.x; ws_[kl][hq * 16 + i * 4 + 1] = f.y;
            ws_[kl][hq * 16 + i * 4 + 2] = f.z; ws_[kl][hq * 16 + i * 4 + 3] = f.w;
        }
    }
    __syncthreads();

    const int h = t & 63, quarter = t >> 6;
    const int n = w * 64 + h;
    const int ks = kb * 2 + (quarter >> 1);
    const int k_in0 = (quarter & 1) * 16;
    u16 hib[16], lob[16];
    #pragma unroll
    for (int j = 0; j < 16; ++j) {
        float v = ws_[quarter * 16 + j][h] * scale;
        u16 hi = f2bf_trunc(v);
        hib[j] = hi;
        lob[j] = f2bf_trunc(v - bf2f(hi));
    }
    u16* dst = wtp + (size_t)n * 2048 + ks * 64;
    *(uint4*)(dst + k_in0)          = *(const uint4*)&hib[0];
    *(uint4*)(dst + k_in0 + 8)      = *(const uint4*)&hib[8];
    *(uint4*)(dst + 32 + k_in0)     = *(const uint4*)&lob[0];
    *(uint4*)(dst + 32 + k_in0 + 8) = *(const uint4*)&lob[8];
}

// ---------------- Projection GEMM (round-11 best): 512x256, 3-stage, vmcnt(4) ----------------
#define NKS 32
#define XB(P) (smem + (P) * 4096)
#define BB(P) (smem + 12288 + (P) * 12288)

__global__ __launch_bounds__(256) void proj_gemm(
    const float* __restrict__ x, const u16* __restrict__ wtp,
    u16* __restrict__ qh8, u16* __restrict__ ql8,
    u16* __restrict__ kth, u16* __restrict__ ktl,
    u16* __restrict__ vtt)
{
    __shared__ __align__(16) unsigned char smem[49152];  // 3 x (4KB x + 12KB W)

    const int tid  = threadIdx.x;
    const int wave = tid >> 6, lane = tid & 63;
    const int lo4  = lane & 15, g = lane >> 4;
    const int ch   = blockIdx.x >> 8;          // col half: 0 or 1
    const int row0 = (blockIdx.x & 255) * 32;
    const int rt   = wave >> 1;                // row-tile 0/1
    const int cbase = (wave & 1) * 3;          // local col-tiles (of 6)
    const int rl = rt * 16 + lo4;
    const int wcol0 = ch * 96;                 // global col base

    f32x4 acc[3];
    #pragma unroll
    for (int c = 0; c < 3; ++c) acc[c] = (f32x4){0.f, 0.f, 0.f, 0.f};

    const int xr = tid >> 3, xc = tid & 7;
    const int xsw = (xc ^ (xr & 7)) << 2;
    const float* xsrc0 = x + (size_t)(row0 + xr) * Dn + xsw;

    #define STAGE(P, KS)                                                     \
        {                                                                    \
            GLL16(xsrc0 + (KS) * 32, XB(P) + tid * 16);                      \
            _Pragma("unroll")                                                \
            for (int i = 0; i < 3; ++i) {                                    \
                const int c = i * 256 + tid;                                 \
                const int n_ = c >> 3, p_ = c & 7;                           \
                const int l_ = p_ ^ (n_ & 7);                                \
                const u16* src = wtp + (size_t)(wcol0 + n_) * 2048 + (KS) * 64 \
                                 + ((l_ & 3) << 3) + ((l_ >> 2) << 5);       \
                GLL16(src, BB(P) + c * 16);                                  \
            }                                                                \
        }

    #define COMPUTE(P, KS)                                                   \
        {                                                                    \
            bf16x8 ah, al;                                                   \
            {                                                                \
                const unsigned char* xb = XB(P) + rl * 128;                  \
                f32x4 f0 = *(const f32x4*)(xb + (((2 * g + 0) ^ (rl & 7)) << 4)); \
                f32x4 f1 = *(const f32x4*)(xb + (((2 * g + 1) ^ (rl & 7)) << 4)); \
                _Pragma("unroll")                                            \
                for (int jj = 0; jj < 4; ++jj) {                             \
                    u16 h0 = f2bf_trunc(f0[jj]);                             \
                    ah[jj] = (short)h0;                                      \
                    al[jj] = (short)f2bf_trunc(f0[jj] - bf2f(h0));           \
                    u16 h1 = f2bf_trunc(f1[jj]);                             \
                    ah[4 + jj] = (short)h1;                                  \
                    al[4 + jj] = (short)f2bf_trunc(f1[jj] - bf2f(h1));       \
                }                                                            \
            }                                                                \
            _Pragma("unroll")                                                \
            for (int ct = 0; ct < 3; ++ct) {                                 \
                const int n = (cbase + ct) * 16 + lo4;                       \
                const unsigned char* bb = BB(P) + n * 128;                   \
                bf16x8 bh = *(const bf16x8*)(bb + (((g)     ^ (n & 7)) << 4)); \
                bf16x8 bl = *(const bf16x8*)(bb + (((4 + g) ^ (n & 7)) << 4)); \
                acc[ct] = __builtin_amdgcn_mfma_f32_16x16x32_bf16(ah, bh, acc[ct], 0, 0, 0); \
                acc[ct] = __builtin_amdgcn_mfma_f32_16x16x32_bf16(al, bh, acc[ct], 0, 0, 0); \
                acc[ct] = __builtin_amdgcn_mfma_f32_16x16x32_bf16(ah, bl, acc[ct], 0, 0, 0); \
            }                                                                \
        }

    STAGE(0, 0)
    STAGE(1, 1)
    int pb = 0;
    for (int ks = 0; ks < NKS; ++ks) {
        if (ks == NKS - 1) {
            asm volatile("s_waitcnt vmcnt(0)" ::: "memory");
        } else {
            asm volatile("s_waitcnt vmcnt(4)" ::: "memory");
        }
        __builtin_amdgcn_s_barrier();
        asm volatile("" ::: "memory");

        int ps = pb + 2; if (ps >= 3) ps -= 3;
        if (ks + 2 < NKS) STAGE(ps, ks + 2)
        COMPUTE(pb, ks)
        pb = (pb == 2) ? 0 : pb + 1;
    }

    // epilogue: C layout col=lane&15, row=g*4+reg; global col = wcol0 + local n
    const int grow = row0 + rt * 16 + g * 4;
    const int bb_ = grow >> 11, tl = grow & 2047;
    #pragma unroll
    for (int ct = 0; ct < 3; ++ct) {
        const int n = wcol0 + (cbase + ct) * 16 + lo4;
        if (n < 64) {
            const int kch = n >> 5, gi = (n >> 3) & 3, e = n & 7;
            const size_t base = (size_t)bb_ * 131072
                + (size_t)(((((tl >> 4) * 2 + kch) * 4 + gi) * 16 + (tl & 15)) * 8 + e);
            #pragma unroll
            for (int reg = 0; reg < 4; ++reg) {
                float v = acc[ct][reg];
                u16 hi = f2bf_trunc(v);
                kth[base + reg * 8] = hi;
                ktl[base + reg * 8] = f2bf_trunc(v - bf2f(hi));
            }
        } else if (n < 128) {
            #pragma unroll
            for (int reg = 0; reg < 4; ++reg) {
                float v = acc[ct][reg];   // already *8 (folded into Wq)
                u16 hi = f2bf_trunc(v);
                qh8[(size_t)(grow + reg) * HSn + (n - 64)] = hi;
                ql8[(size_t)(grow + reg) * HSn + (n - 64)] = f2bf_trunc(v - bf2f(hi));
            }
        } else {
            const int h = n - 128;
            s16x4 pack;
            #pragma unroll
            for (int reg = 0; reg < 4; ++reg)
                pack[reg] = (short)f2bf_rne(acc[ct][reg]);
            const size_t vidx = (size_t)bb_ * 131072
                + (size_t)((tl >> 5) * 2048 + (h >> 4) * 512 + (h & 15) * 32
                           + ((tl >> 3) & 3) * 8 + (tl & 7));
            *(s16x4*)(vtt + vidx) = pack;
        }
    }
}

// ---------------- MFMA flash attention v5: MFMA row-sum + defer-max ----------------
struct KVset {
    bf16x8 kh0[2], kh1[2], kl0[2], kl1[2], vf[4];
};

__global__ __launch_bounds__(256, 2) void attn_kernel(
    const u16* __restrict__ qh8, const u16* __restrict__ ql8,
    const u16* __restrict__ kth, const u16* __restrict__ ktl,
    const u16* __restrict__ vtt, float* __restrict__ out)
{
    __shared__ __align__(16) unsigned char pbuf[4096];
    __shared__ __align__(16) float om_s[4][16][64];
    __shared__ float ml_s[4][16][2];

    const int tid  = threadIdx.x;
    const int wave = tid >> 6, lane = tid & 63;
    const int lo4  = lane & 15, g = lane >> 4;

    const int sblk = blockIdx.x >> 8, c = blockIdx.x & 255;
    const int tb = sblk ? 127 - (c >> 1) : (c >> 1);
    const int b  = 2 * sblk + (c & 1);
    const int t0 = tb * 16;

    const u16* qhp = qh8 + ((size_t)b * Tn + t0) * HSn;
    const u16* qlp = ql8 + ((size_t)b * Tn + t0) * HSn;
    const u16* kthb = kth + (size_t)b * 131072;
    const u16* ktlb = ktl + (size_t)b * 131072;
    const u16* vttb = vtt + (size_t)b * 131072;
    const int klane = lane * 8;
    const int vlane = lo4 * 32 + g * 8;

    bf16x8 qfh[2], qfl[2];
    #pragma unroll
    for (int ch = 0; ch < 2; ++ch) {
        qfh[ch] = *(const bf16x8*)(qhp + lo4 * HSn + ch * 32 + g * 8);
        qfl[ch] = *(const bf16x8*)(qlp + lo4 * HSn + ch * 32 + g * 8);
    }

    bf16x8 vones;
    #pragma unroll
    for (int i = 0; i < 8; ++i) vones[i] = (short)0x3F80;   // bf16 1.0

    f32x4 O[4];
    #pragma unroll
    for (int n = 0; n < 4; ++n) O[n] = (f32x4){0.f, 0.f, 0.f, 0.f};
    float mrow[4], lrow[4];
    #pragma unroll
    for (int r = 0; r < 4; ++r) { mrow[r] = -1e30f; lrow[r] = 0.f; }

    const int nt = (t0 + 15) / 32 + 1;
    unsigned char* myPB = pbuf + wave * 1024;

    #define LOADSET(S, J)                                                     \
        {                                                                     \
            const u16* kb_ = kthb + (size_t)(2 * (J)) * 1024 + klane;         \
            const u16* lb_ = ktlb + (size_t)(2 * (J)) * 1024 + klane;         \
            S.kh0[0] = *(const bf16x8*)(kb_);                                 \
            S.kh1[0] = *(const bf16x8*)(kb_ + 512);                           \
            S.kh0[1] = *(const bf16x8*)(kb_ + 1024);                          \
            S.kh1[1] = *(const bf16x8*)(kb_ + 1536);                          \
            S.kl0[0] = *(const bf16x8*)(lb_);                                 \
            S.kl1[0] = *(const bf16x8*)(lb_ + 512);                           \
            S.kl0[1] = *(const bf16x8*)(lb_ + 1024);                          \
            S.kl1[1] = *(const bf16x8*)(lb_ + 1536);                          \
            const u16* vb_ = vttb + (size_t)(J) * 2048 + vlane;               \
            S.vf[0] = *(const bf16x8*)(vb_);                                  \
            S.vf[1] = *(const bf16x8*)(vb_ + 512);                            \
            S.vf[2] = *(const bf16x8*)(vb_ + 1024);                           \
            S.vf[3] = *(const bf16x8*)(vb_ + 1536);                           \
        }

    #define COMPUTE_ATT(S, J)                                                 \
        {                                                                     \
            const int s0 = (J) * 32;                                          \
            f32x4 accS[2];                                                    \
            __builtin_amdgcn_s_setprio(1);                                    \
            _Pragma("unroll")                                                 \
            for (int sb = 0; sb < 2; ++sb) {                                  \
                f32x4 a = (f32x4){0.f, 0.f, 0.f, 0.f};                        \
                a = __builtin_amdgcn_mfma_f32_16x16x32_bf16(qfh[0], S.kh0[sb], a, 0, 0, 0); \
                a = __builtin_amdgcn_mfma_f32_16x16x32_bf16(qfh[1], S.kh1[sb], a, 0, 0, 0); \
                a = __builtin_amdgcn_mfma_f32_16x16x32_bf16(qfl[0], S.kh0[sb], a, 0, 0, 0); \
                a = __builtin_amdgcn_mfma_f32_16x16x32_bf16(qfl[1], S.kh1[sb], a, 0, 0, 0); \
                a = __builtin_amdgcn_mfma_f32_16x16x32_bf16(qfh[0], S.kl0[sb], a, 0, 0, 0); \
                a = __builtin_amdgcn_mfma_f32_16x16x32_bf16(qfh[1], S.kl1[sb], a, 0, 0, 0); \
                accS[sb] = a;                                                 \
            }                                                                 \
            __builtin_amdgcn_s_setprio(0);                                    \
            float v0s[4], v1s[4], mts[4];                                     \
            _Pragma("unroll")                                                 \
            for (int reg = 0; reg < 4; ++reg) {                               \
                const int tg  = t0 + g * 4 + reg;                             \
                v0s[reg] = (s0 + lo4      <= tg) ? accS[0][reg] : -1e30f;     \
                v1s[reg] = (s0 + 16 + lo4 <= tg) ? accS[1][reg] : -1e30f;     \
                float mt = fmaxf(v0s[reg], v1s[reg]);                         \
                mt = fmaxf(mt, __shfl_xor(mt, 1));                            \
                mt = fmaxf(mt, __shfl_xor(mt, 2));                            \
                mt = fmaxf(mt, __shfl_xor(mt, 4));                            \
                mt = fmaxf(mt, __shfl_xor(mt, 8));                            \
                mts[reg] = mt;                                                \
            }                                                                 \
            const bool grew = (mts[0] > mrow[0]) | (mts[1] > mrow[1])         \
                            | (mts[2] > mrow[2]) | (mts[3] > mrow[3]);        \
            if (__any(grew)) {                                                \
                _Pragma("unroll")                                             \
                for (int reg = 0; reg < 4; ++reg) {                           \
                    float mn = fmaxf(mrow[reg], mts[reg]);                    \
                    float alpha = __expf(mrow[reg] - mn);                     \
                    lrow[reg] *= alpha;                                       \
                    mrow[reg] = mn;                                           \
                    _Pragma("unroll")                                         \
                    for (int n = 0; n < 4; ++n) O[n][reg] *= alpha;           \
                }                                                             \
            }                                                                 \
            _Pragma("unroll")                                                 \
            for (int reg = 0; reg < 4; ++reg) {                               \
                const int tg  = t0 + g * 4 + reg;                             \
                float p0 = (s0 + lo4      <= tg) ? __expf(v0s[reg] - mrow[reg]) : 0.f; \
                float p1 = (s0 + 16 + lo4 <= tg) ? __expf(v1s[reg] - mrow[reg]) : 0.f; \
                const int irow = g * 4 + reg;                                 \
                *(u16*)(myPB + ((irow * 64 + lo4 * 2) ^ (reg << 4)))      = f2bf_rne(p0); \
                *(u16*)(myPB + ((irow * 64 + 32 + lo4 * 2) ^ (reg << 4))) = f2bf_rne(p1); \
            }                                                                 \
            bf16x8 pf = *(const bf16x8*)(myPB + ((lo4 * 64 + 16 * g) ^ ((lo4 & 3) << 4))); \
            __builtin_amdgcn_s_setprio(1);                                    \
            f32x4 lacc = (f32x4){0.f, 0.f, 0.f, 0.f};                         \
            lacc = __builtin_amdgcn_mfma_f32_16x16x32_bf16(pf, vones, lacc, 0, 0, 0); \
            _Pragma("unroll")                                                 \
            for (int n = 0; n < 4; ++n)                                       \
                O[n] = __builtin_amdgcn_mfma_f32_16x16x32_bf16(pf, S.vf[n], O[n], 0, 0, 0); \
            __builtin_amdgcn_s_setprio(0);                                    \
            _Pragma("unroll")                                                 \
            for (int reg = 0; reg < 4; ++reg) lrow[reg] += lacc[reg];         \
        }

    KVset A, B;
    int j = wave;
    if (j < nt) LOADSET(A, j)
    while (j < nt) {
        if (j + 4 < nt) LOADSET(B, j + 4)
        COMPUTE_ATT(A, j)
        if (j + 4 < nt) {
            if (j + 8 < nt) LOADSET(A, j + 8)
            COMPUTE_ATT(B, j + 4)
        }
        j += 8;
    }

    // per-wave partials -> LDS
    #pragma unroll
    for (int n = 0; n < 4; ++n)
        #pragma unroll
        for (int reg = 0; reg < 4; ++reg)
            om_s[wave][g * 4 + reg][n * 16 + lo4] = O[n][reg];
    if (lo4 == 0) {
        #pragma unroll
        for (int reg = 0; reg < 4; ++reg) {
            ml_s[wave][g * 4 + reg][0] = mrow[reg];
            ml_s[wave][g * 4 + reg][1] = lrow[reg];
        }
    }
    __syncthreads();

    const int r  = tid >> 4;
    const int h4 = (tid & 15) * 4;
    float mw[4], lw[4], mstar = -1e30f;
    #pragma unroll
    for (int w = 0; w < 4; ++w) {
        mw[w] = ml_s[w][r][0];
        lw[w] = ml_s[w][r][1];
        mstar = fmaxf(mstar, mw[w]);
    }
    float lstar = 0.f, ew[4];
    #pragma unroll
    for (int w = 0; w < 4; ++w) { ew[w] = __expf(mw[w] - mstar); lstar += lw[w] * ew[w]; }
    float4 a4 = {0.f, 0.f, 0.f, 0.f};
    #pragma unroll
    for (int w = 0; w < 4; ++w) {
        float4 t4 = *(const float4*)&om_s[w][r][h4];
        a4.x += t4.x * ew[w]; a4.y += t4.y * ew[w];
        a4.z += t4.z * ew[w]; a4.w += t4.w * ew[w];
    }
    const float inv = 1.f / lstar;
    a4.x *= inv; a4.y *= inv; a4.z *= inv; a4.w *= inv;
    *(float4*)(out + ((size_t)b * Tn + t0 + r) * HSn + h4) = a4;
}

extern "C" void kernel_launch(void* const* d_in, const int* in_sizes, int n_in,
                              void* d_out, int out_size, void* d_ws, size_t ws_size,
                              hipStream_t stream) {
    const float* x  = (const float*)d_in[0];
    const float* Wk = (const float*)d_in[1];
    const float* Wq = (const float*)d_in[2];
    const float* Wv = (const float*)d_in[3];
    float* out = (float*)d_out;

    const size_t per = (size_t)Bn * Tn * HSn;   // 524288
    u16* qh8 = (u16*)d_ws;
    u16* ql8 = qh8 + per;
    u16* kth = ql8 + per;
    u16* ktl = kth + per;
    u16* vtt = ktl + per;
    u16* wtp = vtt + per;                       // 192*2048 u16 = 768 KB

    hipLaunchKernelGGL(wprep_kernel, dim3(16, 3), dim3(256), 0, stream,
                       Wk, Wq, Wv, wtp);
    hipLaunchKernelGGL(proj_gemm, dim3(512), dim3(256), 0, stream,
                       x, wtp, qh8, ql8, kth, ktl, vtt);
    hipLaunchKernelGGL(attn_kernel, dim3(512), dim3(256), 0, stream,
                       qh8, ql8, kth, ktl, vtt, out);
}